// Round 3
// baseline (645.385 us; speedup 1.0000x reference)
//
#include <hip/hip_runtime.h>
#include <hip/hip_bf16.h>
#include <stdint.h>

// DEQTrellisNetLM on MI355X (gfx950).
// B=4, L=1024, H=768, 4H=3072, NINP=512, K=2, NLAYER=10, NOUT=256.
//
//  - h time-major (B,L+1,H) bf16; c time-major (B,L+1,H) fp16. Row 0 = z0.
//  - Weights pre-permuted (N,K) bf16, gate-interleaved cols o'=(j>>4)*64+gate*16+(j&15).
//  - us precomputed once as fp16x4 gate-gathered: us4[m][j] = {i,o,g,f} (+ both biases).
//  - GEMM: 256x256 tile, BK=32, 8 waves (2Mx4N), 4-deep LDS pipeline with
//    counted vmcnt(8) (T4), XOR-swizzled staging/reads (T2, both-sides rule #21),
//    setprio around MFMA (T5), XCD-bijective block swizzle (T1).

#define B_    4
#define L_    1024
#define LP1   1025
#define H_    768
#define NG_   3072
#define NINP_ 512
#define NOUT_ 256

typedef __bf16 bf16x8 __attribute__((ext_vector_type(8)));
typedef float f32x4 __attribute__((ext_vector_type(4)));
typedef _Float16 f16x4 __attribute__((ext_vector_type(4)));
using bf16_t = __hip_bfloat16;

__device__ __forceinline__ float sigf(float x){ return 1.f/(1.f + __expf(-x)); }
__device__ __forceinline__ float tanhf_(float x){
  float e = __expf(-2.f*fabsf(x));
  float r = (1.f - e)/(1.f + e);
  return x >= 0.f ? r : -r;
}

__device__ __forceinline__ void gl_lds16(const void* g, void* l){
  __builtin_amdgcn_global_load_lds(
    (const __attribute__((address_space(1))) uint32_t*)g,
    (__attribute__((address_space(3))) uint32_t*)l, 16, 0, 0);
}

// ---- init: zero Xt row0, set h/c row0 from z0 ----
__global__ void init_k(const float* __restrict__ z0, bf16_t* __restrict__ Xt,
                       bf16_t* __restrict__ Hb0, bf16_t* __restrict__ Hb1,
                       _Float16* __restrict__ Cb0, _Float16* __restrict__ Cb1){
  int tid = blockIdx.x*256 + threadIdx.x;
  if (tid < B_*NINP_){
    int b = tid >> 9, i = tid & 511;
    Xt[(size_t)b*LP1*NINP_ + i] = __float2bfloat16(0.f);
  }
  if (tid < B_*H_){
    int b = tid / H_, j = tid % H_;
    size_t idx = (size_t)b*LP1*H_ + j;
    bf16_t hz = __float2bfloat16(z0[b*2*H_ + j]);
    _Float16 cz = (_Float16)z0[b*2*H_ + H_ + j];
    Hb0[idx] = hz; Hb1[idx] = hz; Cb0[idx] = cz; Cb1[idx] = cz;
  }
}

// ---- weight prep: permute + transpose + bf16; biases gathered per-j float4 ----
__global__ void prep_w(const float* __restrict__ iw, const float* __restrict__ ib,
                       const float* __restrict__ cw, const float* __restrict__ cb,
                       bf16_t* __restrict__ Wit, bf16_t* __restrict__ Wct,
                       float* __restrict__ bias4){
  int op = blockIdx.x;
  int gate = (op >> 4) & 3;
  int j = ((op >> 6) << 4) | (op & 15);
  int o = gate*H_ + j;
  const float2* s2 = (const float2*)(iw + (size_t)o*NINP_*2);
  bf16_t* d = Wit + (size_t)op*(2*NINP_);
  for (int i = threadIdx.x; i < NINP_; i += 256){
    float2 v = s2[i];
    d[i]         = __float2bfloat16(v.x);   // tap k=0 (t-1)
    d[NINP_ + i] = __float2bfloat16(v.y);   // tap k=1 (t)
  }
  const float2* c2 = (const float2*)(cw + (size_t)o*H_*2);
  bf16_t* dc = Wct + (size_t)op*(2*H_);
  for (int i = threadIdx.x; i < H_; i += 256){
    float2 v = c2[i];
    dc[i]      = __float2bfloat16(v.x);
    dc[H_ + i] = __float2bfloat16(v.y);
  }
  if (threadIdx.x == 0) bias4[j*4 + gate] = ib[o] + cb[o];
}

// ---- X (B,512,1024) f32 -> Xt (B,1025,512) bf16, Xt[b][t+1][i] = X[b][i][t] ----
__global__ void transpose_x(const float* __restrict__ X, bf16_t* __restrict__ Xt){
  __shared__ float tile[64][65];
  int b = blockIdx.z;
  int t0 = blockIdx.x*64, i0 = blockIdx.y*64;
  int c = threadIdx.x & 63;
  for (int r = threadIdx.x >> 6; r < 64; r += 4)
    tile[r][c] = X[((size_t)b*NINP_ + i0 + r)*L_ + t0 + c];
  __syncthreads();
  for (int r = threadIdx.x >> 6; r < 64; r += 4)
    Xt[((size_t)b*LP1 + t0 + r + 1)*NINP_ + i0 + c] = __float2bfloat16(tile[c][r]);
}

// ---- 256^2 8-wave GEMM, 4-deep counted-vmcnt pipeline ----
// MODE 0: us4 = f16x4 gather of A*Bt + bias   (A=Xt, K=1024)
// MODE 1: gates(A*Bt + us4) -> Hnew/Cnew      (A=Hprev, K=1536)
template<int KTOT, int AROW, int MODE>
__launch_bounds__(512, 2)
__global__ void gemm8(const bf16_t* __restrict__ A, const bf16_t* __restrict__ Bt,
                      const float* __restrict__ bias4, f16x4* __restrict__ us4,
                      const _Float16* __restrict__ Cprev, _Float16* __restrict__ Cnew,
                      bf16_t* __restrict__ Hnew){
  extern __shared__ char smem[];
  char* AsB = smem;            // 4 slots x 16KB (256 rows x 64B)
  char* BsB = smem + 65536;    // 4 slots x 16KB

  const int tid = threadIdx.x;
  const int l  = tid & 63;
  const int w  = tid >> 6;          // 0..7
  const int wm = w >> 2, wn = w & 3;

  // XCD-bijective swizzle: nwg = 192, 192 % 8 == 0
  const int nwg = gridDim.x * gridDim.y;
  int flat = blockIdx.y * gridDim.x + blockIdx.x;
  flat = (flat & 7) * (nwg >> 3) + (flat >> 3);
  const int bm0 = (flat & 15) * 256;      // gridDim.x == 16 (M blocks)
  const int bn0 = (flat >> 4) * 256;

  f32x4 acc[8][4];
#pragma unroll
  for (int i = 0; i < 8; ++i)
#pragma unroll
    for (int jj = 0; jj < 4; ++jj)
      acc[i][jj] = (f32x4){0.f,0.f,0.f,0.f};

  // Staging: per K-tile 2 A-rounds + 2 B-rounds of 8KB (512 thr x 16B).
  // LDS dest linear: row r=(n*8+w)*16+(l>>2), slot s=l&3. Source k-group is
  // inverse-swizzled: kg = s ^ ((r>>2)&3) = (l&3) ^ ((l>>4)&3).
  const int kgs = (l & 3) ^ ((l >> 4) & 3);
  const char* ag[2]; const char* bg[2];
  int al[2];
#pragma unroll
  for (int n = 0; n < 2; ++n){
    const int r = (n*8 + w)*16 + (l >> 2);
    const int m = bm0 + r;
    const int b = m >> 10, t = m & 1023;
    ag[n] = (const char*)A + (size_t)(b*LP1 + t)*(AROW*2) + kgs*16;
    bg[n] = (const char*)Bt + (size_t)(bn0 + r)*(KTOT*2) + kgs*16;
    al[n] = (n*8 + w)*1024;
  }

  // Fragment reads: row = (wm*128|wn*64) + f*16 + lr, k-group kg = l>>4,
  // swizzled byte = row*64 + ((kg ^ ((lr>>2)&3))<<4)  [row>>2 & 3 == lr>>2 & 3]
  const int lr = l & 15, kg = l >> 4;
  const int xq = (kg ^ ((lr >> 2) & 3)) << 4;
  const int aoff = (wm*128 + lr)*64 + xq;
  const int boff = (wn*64  + lr)*64 + xq;

#define STAGE(T) { \
    char* ad = AsB + (((T) & 3) << 14); \
    char* bd = BsB + (((T) & 3) << 14); \
    const int ko = (T) << 6; \
    gl_lds16(ag[0] + ko, ad + al[0]); \
    gl_lds16(ag[1] + ko, ad + al[1]); \
    gl_lds16(bg[0] + ko, bd + al[0]); \
    gl_lds16(bg[1] + ko, bd + al[1]); }

#define COMPUTE(T) { \
    const char* ab = AsB + (((T) & 3) << 14); \
    const char* bb = BsB + (((T) & 3) << 14); \
    bf16x8 af[8], bv[4]; \
    _Pragma("unroll") for (int f = 0; f < 8; ++f) \
      af[f] = *(const bf16x8*)(ab + aoff + f*1024); \
    _Pragma("unroll") for (int f = 0; f < 4; ++f) \
      bv[f] = *(const bf16x8*)(bb + boff + f*1024); \
    __builtin_amdgcn_s_setprio(1); \
    _Pragma("unroll") for (int fm = 0; fm < 8; ++fm) \
      _Pragma("unroll") for (int fn = 0; fn < 4; ++fn) \
        acc[fm][fn] = __builtin_amdgcn_mfma_f32_16x16x32_bf16(af[fm], bv[fn], acc[fm][fn], 0, 0, 0); \
    __builtin_amdgcn_s_setprio(0); }

  constexpr int NT = KTOT / 32;

  // prologue: 3 tiles in flight
  STAGE(0) STAGE(1) STAGE(2)
  asm volatile("s_waitcnt vmcnt(8)" ::: "memory");   // tile 0 complete
  __builtin_amdgcn_s_barrier();

  for (int t = 0; t < NT - 3; ++t){
    STAGE(t+3)                                       // slot (t+3)&3 freed at step t-1
    COMPUTE(t)
    asm volatile("s_waitcnt vmcnt(8)" ::: "memory"); // tile t+1 complete, t+2/t+3 in flight
    __builtin_amdgcn_s_barrier();
  }
  COMPUTE(NT-3)
  asm volatile("s_waitcnt vmcnt(4)" ::: "memory");
  __builtin_amdgcn_s_barrier();
  COMPUTE(NT-2)
  asm volatile("s_waitcnt vmcnt(0)" ::: "memory");
  __builtin_amdgcn_s_barrier();
  COMPUTE(NT-1)

#undef STAGE
#undef COMPUTE

  const int jblk = (bn0 >> 6) + wn;
  const int j = jblk*16 + lr;
  const int rq = kg << 2;

  if (MODE == 0){
    const float4 bz = ((const float4*)bias4)[j];
#pragma unroll
    for (int fm = 0; fm < 8; ++fm){
      const int mbase = bm0 + wm*128 + fm*16 + rq;
#pragma unroll
      for (int r = 0; r < 4; ++r){
        const int m = mbase + r;
        f16x4 v = { (_Float16)(acc[fm][0][r] + bz.x), (_Float16)(acc[fm][1][r] + bz.y),
                    (_Float16)(acc[fm][2][r] + bz.z), (_Float16)(acc[fm][3][r] + bz.w) };
        us4[(size_t)m*H_ + j] = v;
      }
    }
  } else {
#pragma unroll
    for (int fm = 0; fm < 8; ++fm){
      const int mbase = bm0 + wm*128 + fm*16 + rq;
      f16x4 uv[4]; _Float16 cp16[4]; size_t hcb[4];
#pragma unroll
      for (int r = 0; r < 4; ++r){
        const int m = mbase + r;
        const int b = m >> 10, t = m & 1023;
        uv[r] = us4[(size_t)m*H_ + j];
        hcb[r] = (size_t)(b*LP1 + t)*H_ + j;
        cp16[r] = Cprev[hcb[r]];
      }
#pragma unroll
      for (int r = 0; r < 4; ++r){
        const float ig = acc[fm][0][r] + (float)uv[r][0];
        const float og = acc[fm][1][r] + (float)uv[r][1];
        const float gg = acc[fm][2][r] + (float)uv[r][2];
        const float fg = acc[fm][3][r] + (float)uv[r][3];
        const float c  = sigf(fg)*(float)cp16[r] + sigf(ig)*tanhf_(gg);
        const float h  = sigf(og)*tanhf_(c);
        Cnew[hcb[r] + H_] = (_Float16)c;          // row t+1
        Hnew[hcb[r] + H_] = __float2bfloat16(h);
      }
    }
  }
}

// ---- iteration 0: h=0 (c_prev=z0c at t=0) -> elementwise gates on us4 ----
__global__ void iter0_k(const f16x4* __restrict__ us4, bf16_t* __restrict__ Hn,
                        _Float16* __restrict__ Cn){
  const int m = blockIdx.y;
  const int j = blockIdx.x*256 + threadIdx.x;
  const int b = m >> 10, t = m & 1023;
  f16x4 u = us4[(size_t)m*H_ + j];
  const float ig = (float)u[0], og = (float)u[1], gg = (float)u[2], fg = (float)u[3];
  float cp = (t == 0) ? (float)Cn[(size_t)b*LP1*H_ + j] : 0.f;
  const float c = sigf(fg)*cp + sigf(ig)*tanhf_(gg);
  const float h = sigf(og)*tanhf_(c);
  const size_t idx = (size_t)(b*LP1 + t + 1)*H_ + j;
  Cn[idx] = (_Float16)c;
  Hn[idx] = __float2bfloat16(h);
}

// ---- finalize: out (B,L,NOUT) + z0_out (B,2H) from it9 h/c ----
__global__ void finalize_k(const bf16_t* __restrict__ Hf, const _Float16* __restrict__ Cf,
                           float* __restrict__ out){
  const int tid = blockIdx.x*256 + threadIdx.x;
  if (tid < B_*L_*NOUT_){
    const int n = tid & 255, t = (tid >> 8) & 1023, b = tid >> 18;
    out[tid] = __bfloat162float(Hf[((size_t)b*LP1 + t + 1)*H_ + (H_ - NOUT_) + n]);
  } else if (tid < B_*L_*NOUT_ + B_*2*H_){
    const int r = tid - B_*L_*NOUT_;
    const int b = r / (2*H_), ch = r % (2*H_);
    const size_t row = ((size_t)b*LP1 + L_)*H_;
    out[tid] = (ch < H_) ? __bfloat162float(Hf[row + ch]) : (float)Cf[row + (ch - H_)];
  }
}

extern "C" void kernel_launch(void* const* d_in, const int* in_sizes, int n_in,
                              void* d_out, int out_size, void* d_ws, size_t ws_size,
                              hipStream_t stream){
  const float* X   = (const float*)d_in[0];
  const float* z0  = (const float*)d_in[1];
  const float* iw  = (const float*)d_in[2];
  const float* ib  = (const float*)d_in[3];
  const float* cw  = (const float*)d_in[4];
  const float* cbv = (const float*)d_in[5];
  float* out = (float*)d_out;

  char* ws = (char*)d_ws;
  f16x4*    us4  = (f16x4*)   (ws + 0);           // 4096*768*8  = 25165824
  bf16_t*   Xt   = (bf16_t*)  (ws + 25165824);    // 4*1025*512*2 = 4198400
  bf16_t*   Wit  = (bf16_t*)  (ws + 29364224);    // 3072*1024*2 = 6291456
  bf16_t*   Wct  = (bf16_t*)  (ws + 35655680);    // 3072*1536*2 = 9437184
  float*    bias4= (float*)   (ws + 45092864);    // 768*4*4 = 12288
  bf16_t*   Hb0  = (bf16_t*)  (ws + 45105152);    // 4*1025*768*2 = 6297600
  bf16_t*   Hb1  = (bf16_t*)  (ws + 51402752);
  _Float16* Cb0  = (_Float16*)(ws + 57700352);    // 4*1025*768*2 = 6297600
  _Float16* Cb1  = (_Float16*)(ws + 63997952);    // end = 70295552 (~67MB)

  hipFuncSetAttribute((const void*)gemm8<1024, NINP_, 0>,
                      hipFuncAttributeMaxDynamicSharedMemorySize, 131072);
  hipFuncSetAttribute((const void*)gemm8<1536, H_, 1>,
                      hipFuncAttributeMaxDynamicSharedMemorySize, 131072);

  init_k<<<12, 256, 0, stream>>>(z0, Xt, Hb0, Hb1, Cb0, Cb1);
  prep_w<<<NG_, 256, 0, stream>>>(iw, ib, cw, cbv, Wit, Wct, bias4);
  transpose_x<<<dim3(L_/64, NINP_/64, B_), 256, 0, stream>>>(X, Xt);

  // inject conv as GEMM: M=4096, N=3072, K=1024 -> us4 (fp16, gate-gathered)
  gemm8<1024, NINP_, 0><<<dim3(16, 12), 512, 131072, stream>>>(
      Xt, Wit, bias4, us4, nullptr, nullptr, nullptr);

  // iteration 0 (h=0): elementwise on us4
  iter0_k<<<dim3(3, 4096), 256, 0, stream>>>(us4, Hb0, Cb0);

  // iterations 1..9: fused GEMM (K=1536) + gates, double-buffered
  bf16_t* Hp = Hb0; _Float16* Cp = Cb0;
  bf16_t* Hn = Hb1; _Float16* Cn = Cb1;
  for (int it = 1; it <= 9; ++it){
    gemm8<1536, H_, 1><<<dim3(16, 12), 512, 131072, stream>>>(
        Hp, Wct, nullptr, us4, Cp, Cn, Hn);
    bf16_t* th = Hp; Hp = Hn; Hn = th;
    _Float16* tc = Cp; Cp = Cn; Cn = tc;
  }

  finalize_k<<<4120, 256, 0, stream>>>(Hp, Cp, out);
}